// Round 3
// baseline (1375.164 us; speedup 1.0000x reference)
//
#include <hip/hip_runtime.h>

// P = 100000 pois, U = 50000 users, NNZ = 2000000, D = 128, 3 layers.
// CSR build per launch (hist -> scan -> scatter of packed int2 (col,val)),
// then gather SpMM: 32 lanes/row, float4 per lane, register accumulation.
#define DD 128
#define NUM_LAYERS 3
#define SCAN_B 1024

// ---- CSR build ------------------------------------------------------------

__global__ void hist_kernel(const int* __restrict__ up_rows,
                            const int* __restrict__ up_cols,
                            int* __restrict__ cnt, int nnz, int U) {
    int e = blockIdx.x * blockDim.x + threadIdx.x;
    if (e >= nnz) return;
    atomicAdd(&cnt[up_rows[e]], 1);        // user-side bin
    atomicAdd(&cnt[U + up_cols[e]], 1);    // poi-side bin
}

__global__ void scan_blocks_kernel(const int* __restrict__ in, int* __restrict__ out,
                                   int* __restrict__ bsums, int n) {
    __shared__ int tmp[SCAN_B];
    const int tid = threadIdx.x;
    const int gid = blockIdx.x * SCAN_B + tid;
    const int v = (gid < n) ? in[gid] : 0;
    tmp[tid] = v;
    __syncthreads();
    for (int ofs = 1; ofs < SCAN_B; ofs <<= 1) {
        int t = (tid >= ofs) ? tmp[tid - ofs] : 0;
        __syncthreads();
        tmp[tid] += t;
        __syncthreads();
    }
    if (gid < n) out[gid] = tmp[tid] - v;            // exclusive
    if (tid == SCAN_B - 1) bsums[blockIdx.x] = tmp[tid];
}

__global__ void scan_sums_kernel(int* __restrict__ bsums, int nb) {
    __shared__ int tmp[SCAN_B];
    const int tid = threadIdx.x;
    const int v = (tid < nb) ? bsums[tid] : 0;
    tmp[tid] = v;
    __syncthreads();
    for (int ofs = 1; ofs < SCAN_B; ofs <<= 1) {
        int t = (tid >= ofs) ? tmp[tid - ofs] : 0;
        __syncthreads();
        tmp[tid] += t;
        __syncthreads();
    }
    if (tid < nb) bsums[tid] = tmp[tid] - v;
}

__global__ void scan_add_kernel(int* __restrict__ off, const int* __restrict__ bsums,
                                const int* __restrict__ cnt, int* __restrict__ cursor, int n) {
    const int gid = blockIdx.x * SCAN_B + threadIdx.x;
    if (gid >= n) return;
    const int v = off[gid] + bsums[blockIdx.x];
    off[gid] = v;
    cursor[gid] = v;
    if (gid == n - 1) off[n] = v + cnt[gid];
}

// Packed scatter: one 8B (col, val_bits) write per edge-side.
__global__ void scatter_kernel(const int* __restrict__ up_rows,
                               const int* __restrict__ up_cols,
                               const float* __restrict__ up_vals,
                               const float* __restrict__ pu_vals,
                               int* __restrict__ cursor,
                               int2* __restrict__ adj,
                               int nnz, int U) {
    int e = blockIdx.x * blockDim.x + threadIdx.x;
    if (e >= nnz) return;
    const int u = up_rows[e];
    const int p = up_cols[e];
    const int pos = atomicAdd(&cursor[u], 1);
    adj[pos] = make_int2(p, __float_as_int(up_vals[e]));
    const int pos2 = atomicAdd(&cursor[U + p], 1);
    adj[pos2] = make_int2(u, __float_as_int(pu_vals[e]));
}

// ---- SpMM: 32 lanes per row, float4 per lane ------------------------------

__global__ void spmm_kernel(const int* __restrict__ off,
                            const int2* __restrict__ adj,
                            const float* __restrict__ src,
                            float* __restrict__ dst,
                            int base, int nrows) {
    const int rg   = threadIdx.x >> 5;
    const int lane = threadIdx.x & 31;
    const int row  = blockIdx.x * 8 + rg;
    if (row >= nrows) return;
    const int start = off[base + row];
    const int end   = off[base + row + 1];
    const float4* src4 = (const float4*)src;
    float4 acc = {0.f, 0.f, 0.f, 0.f};
    int k = start;
    for (; k + 1 < end; k += 2) {
        const int2 cv0 = adj[k];
        const int2 cv1 = adj[k + 1];
        const float4 x0 = src4[(size_t)cv0.x * 32 + lane];
        const float4 x1 = src4[(size_t)cv1.x * 32 + lane];
        const float v0 = __int_as_float(cv0.y);
        const float v1 = __int_as_float(cv1.y);
        acc.x += v0 * x0.x + v1 * x1.x;
        acc.y += v0 * x0.y + v1 * x1.y;
        acc.z += v0 * x0.z + v1 * x1.z;
        acc.w += v0 * x0.w + v1 * x1.w;
    }
    if (k < end) {
        const int2 cv = adj[k];
        const float4 xv = src4[(size_t)cv.x * 32 + lane];
        const float v = __int_as_float(cv.y);
        acc.x += v * xv.x; acc.y += v * xv.y;
        acc.z += v * xv.z; acc.w += v * xv.w;
    }
    ((float4*)dst)[(size_t)row * 32 + lane] = acc;
}

// Fused: prop gather + residual + acc update.
// xn = prop + x_src[row]; x_dst[row] = xn; out[row] = (out_prev[row] + xn) * scale
__global__ void spmm_fused_kernel(const int* __restrict__ off,
                                  const int2* __restrict__ adj,
                                  const float* __restrict__ src,
                                  const float* __restrict__ x_src,
                                  float* __restrict__ x_dst,
                                  const float* __restrict__ out_prev,
                                  float* __restrict__ out,
                                  float scale, int base, int nrows) {
    const int rg   = threadIdx.x >> 5;
    const int lane = threadIdx.x & 31;
    const int row  = blockIdx.x * 8 + rg;
    if (row >= nrows) return;
    const int start = off[base + row];
    const int end   = off[base + row + 1];
    const float4* src4 = (const float4*)src;
    float4 acc = {0.f, 0.f, 0.f, 0.f};
    int k = start;
    for (; k + 1 < end; k += 2) {
        const int2 cv0 = adj[k];
        const int2 cv1 = adj[k + 1];
        const float4 x0 = src4[(size_t)cv0.x * 32 + lane];
        const float4 x1 = src4[(size_t)cv1.x * 32 + lane];
        const float v0 = __int_as_float(cv0.y);
        const float v1 = __int_as_float(cv1.y);
        acc.x += v0 * x0.x + v1 * x1.x;
        acc.y += v0 * x0.y + v1 * x1.y;
        acc.z += v0 * x0.z + v1 * x1.z;
        acc.w += v0 * x0.w + v1 * x1.w;
    }
    if (k < end) {
        const int2 cv = adj[k];
        const float4 xv = src4[(size_t)cv.x * 32 + lane];
        const float v = __int_as_float(cv.y);
        acc.x += v * xv.x; acc.y += v * xv.y;
        acc.z += v * xv.z; acc.w += v * xv.w;
    }
    const size_t idx = (size_t)row * 32 + lane;
    const float4 xo = ((const float4*)x_src)[idx];
    float4 xn = {acc.x + xo.x, acc.y + xo.y, acc.z + xo.z, acc.w + xo.w};
    ((float4*)x_dst)[idx] = xn;
    const float4 po = ((const float4*)out_prev)[idx];
    float4 ov = {(po.x + xn.x) * scale, (po.y + xn.y) * scale,
                 (po.z + xn.z) * scale, (po.w + xn.w) * scale};
    ((float4*)out)[idx] = ov;
}

// ---- launch ---------------------------------------------------------------

extern "C" void kernel_launch(void* const* d_in, const int* in_sizes, int n_in,
                              void* d_out, int out_size, void* d_ws, size_t ws_size,
                              hipStream_t stream) {
    const float* embs    = (const float*)d_in[0];
    const int*   up_rows = (const int*)d_in[2];
    const int*   up_cols = (const int*)d_in[3];
    const float* up_vals = (const float*)d_in[4];
    const float* pu_vals = (const float*)d_in[5];

    const int NNZ = in_sizes[2];
    const int P   = in_sizes[0] / DD;
    const int U   = 50000;            // fixed problem size (device scalar not host-readable)
    const int N   = U + P;

    float* out = (float*)d_out;

    char* ws = (char*)d_ws;
    size_t o = 0;
    auto alloc = [&](size_t bytes) { size_t r = o; o = (o + bytes + 255) & ~255ULL; return r; };
    int*   cnt    = (int*)  (ws + alloc((size_t)N * 4));
    int*   off    = (int*)  (ws + alloc((size_t)(N + 1) * 4));
    int*   cursor = (int*)  (ws + alloc((size_t)N * 4));
    int*   bsums  = (int*)  (ws + alloc((size_t)SCAN_B * 4));
    int2*  adj    = (int2*) (ws + alloc((size_t)2 * NNZ * 8));
    float* A      = (float*)(ws + alloc((size_t)P * DD * 4));   // x
    float* msg    = (float*)(ws + alloc((size_t)U * DD * 4));   // [U, D]

    const int NB = (N + SCAN_B - 1) / SCAN_B;
    const int edge_blocks = (NNZ + 255) / 256;

    // --- CSR build ---
    hipMemsetAsync(cnt, 0, (size_t)N * 4, stream);
    hist_kernel<<<edge_blocks, 256, 0, stream>>>(up_rows, up_cols, cnt, NNZ, U);
    scan_blocks_kernel<<<NB, SCAN_B, 0, stream>>>(cnt, off, bsums, N);
    scan_sums_kernel<<<1, SCAN_B, 0, stream>>>(bsums, NB);
    scan_add_kernel<<<NB, SCAN_B, 0, stream>>>(off, bsums, cnt, cursor, N);
    scatter_kernel<<<edge_blocks, 256, 0, stream>>>(up_rows, up_cols, up_vals, pu_vals,
                                                    cursor, adj, NNZ, U);

    const int ublocks = (U + 7) / 8;
    const int pblocks = (P + 7) / 8;

    // --- 3 layers (layer 0 reads embs directly; no init memcpys) ---
    for (int layer = 0; layer < NUM_LAYERS; ++layer) {
        const float* xsrc = (layer == 0) ? embs : A;
        const float* oprev = (layer == 0) ? embs : out;
        const float scale = (layer == NUM_LAYERS - 1) ? (1.0f / (NUM_LAYERS + 1)) : 1.0f;
        // msg = HG_up @ x
        spmm_kernel<<<ublocks, 256, 0, stream>>>(off, adj, xsrc, msg, 0, U);
        // xn = HG_pu @ msg + x ; out = (out_prev + xn) * scale
        spmm_fused_kernel<<<pblocks, 256, 0, stream>>>(off, adj, msg, xsrc, A,
                                                       oprev, out, scale, U, P);
    }
}

// Round 4
// 1265.154 us; speedup vs baseline: 1.0870x; 1.0870x over previous
//
#include <hip/hip_runtime.h>

// P = 100000 pois, U = 50000 users, NNZ = 2000000, D = 128, 3 layers.
// Build CSR via two-pass binned scatter (bucket = 128 destination rows),
// then gather SpMM with bf16 operands (fp32 accumulation).
// out = x0 + 0.75*p1 + 0.5*p2 + 0.25*p3  ==  (x0+x1+x2+x3)/4.
#define DD 128
#define NUM_LAYERS 3
#define SCAN_B 1024
#define BKT_SHIFT 7
#define BKT_ROWS 128
#define BKT_CAP 6144   // max bucket ~5120 (binomial, sigma~71) -> 14 sigma margin

typedef unsigned int uint;

__device__ __forceinline__ uint f2bf(float f) {   // fp32 -> bf16 bits, RNE
    uint u = __float_as_uint(f);
    return (u + 0x7fffu + ((u >> 16) & 1u)) >> 16;
}
__device__ __forceinline__ uint pk2(float a, float b) {
    return f2bf(a) | (f2bf(b) << 16);
}
__device__ __forceinline__ void fma8(float acc[8], uint4 q, float v) {
    acc[0] += v * __uint_as_float(q.x << 16);
    acc[1] += v * __uint_as_float(q.x & 0xffff0000u);
    acc[2] += v * __uint_as_float(q.y << 16);
    acc[3] += v * __uint_as_float(q.y & 0xffff0000u);
    acc[4] += v * __uint_as_float(q.z << 16);
    acc[5] += v * __uint_as_float(q.z & 0xffff0000u);
    acc[6] += v * __uint_as_float(q.w << 16);
    acc[7] += v * __uint_as_float(q.w & 0xffff0000u);
}

// ---- CSR build: two-pass binned scatter -----------------------------------

// Pass 1: append each edge-side into its destination-row bucket.
// Entry: .x = (row_low7 << 25) | src_col (src_col < 150000 < 2^25), .y = val bits.
__global__ void pass1_kernel(const int* __restrict__ up_rows,
                             const int* __restrict__ up_cols,
                             const float* __restrict__ up_vals,
                             const float* __restrict__ pu_vals,
                             int* __restrict__ bkcur,
                             int2* __restrict__ stage,
                             int nnz, int U) {
    const int e = blockIdx.x * blockDim.x + threadIdx.x;
    if (e >= nnz) return;
    const int u = up_rows[e];
    const int p = up_cols[e];
    const int pc = U + p;                       // combined p-side row id
    const int bu = u >> BKT_SHIFT;
    const int bp = pc >> BKT_SHIFT;
    int pos = atomicAdd(&bkcur[bu], 1);
    if (pos < BKT_CAP)
        stage[(size_t)bu * BKT_CAP + pos] =
            make_int2(((u & (BKT_ROWS - 1)) << 25) | p, __float_as_int(up_vals[e]));
    int pos2 = atomicAdd(&bkcur[bp], 1);
    if (pos2 < BKT_CAP)
        stage[(size_t)bp * BKT_CAP + pos2] =
            make_int2(((pc & (BKT_ROWS - 1)) << 25) | u, __float_as_int(pu_vals[e]));
}

// Bucket-local histogram -> per-row counts (replaces random global atomics).
__global__ void hist2_kernel(const int* __restrict__ bkcur,
                             const int2* __restrict__ stage,
                             int* __restrict__ cnt, int N) {
    __shared__ int lc[BKT_ROWS];
    const int b = blockIdx.x;
    if (threadIdx.x < BKT_ROWS) lc[threadIdx.x] = 0;
    __syncthreads();
    const int n = min(bkcur[b], BKT_CAP);
    const int2* bs = stage + (size_t)b * BKT_CAP;
    for (int i = threadIdx.x; i < n; i += blockDim.x)
        atomicAdd(&lc[((uint)bs[i].x) >> 25], 1);
    __syncthreads();
    const int r = b * BKT_ROWS + threadIdx.x;
    if (threadIdx.x < BKT_ROWS && r < N) cnt[r] = lc[threadIdx.x];
}

__global__ void scan_blocks_kernel(const int* __restrict__ in, int* __restrict__ out,
                                   int* __restrict__ bsums, int n) {
    __shared__ int tmp[SCAN_B];
    const int tid = threadIdx.x;
    const int gid = blockIdx.x * SCAN_B + tid;
    const int v = (gid < n) ? in[gid] : 0;
    tmp[tid] = v;
    __syncthreads();
    for (int ofs = 1; ofs < SCAN_B; ofs <<= 1) {
        int t = (tid >= ofs) ? tmp[tid - ofs] : 0;
        __syncthreads();
        tmp[tid] += t;
        __syncthreads();
    }
    if (gid < n) out[gid] = tmp[tid] - v;
    if (tid == SCAN_B - 1) bsums[blockIdx.x] = tmp[tid];
}

__global__ void scan_sums_kernel(int* __restrict__ bsums, int nb) {
    __shared__ int tmp[SCAN_B];
    const int tid = threadIdx.x;
    const int v = (tid < nb) ? bsums[tid] : 0;
    tmp[tid] = v;
    __syncthreads();
    for (int ofs = 1; ofs < SCAN_B; ofs <<= 1) {
        int t = (tid >= ofs) ? tmp[tid - ofs] : 0;
        __syncthreads();
        tmp[tid] += t;
        __syncthreads();
    }
    if (tid < nb) bsums[tid] = tmp[tid] - v;
}

__global__ void scan_add_kernel(int* __restrict__ off, const int* __restrict__ bsums,
                                const int* __restrict__ cnt, int n) {
    const int gid = blockIdx.x * SCAN_B + threadIdx.x;
    if (gid >= n) return;
    const int v = off[gid] + bsums[blockIdx.x];
    off[gid] = v;
    if (gid == n - 1) off[n] = v + cnt[gid];
}

// Pass 2: bucket -> final CSR positions (LDS cursors, writes land in a
// contiguous ~40KB window per bucket).
__global__ void pass2_kernel(const int* __restrict__ bkcur,
                             const int2* __restrict__ stage,
                             const int* __restrict__ off,
                             int2* __restrict__ adj, int N) {
    __shared__ int lcur[BKT_ROWS];
    const int b = blockIdx.x;
    const int r = b * BKT_ROWS + threadIdx.x;
    if (threadIdx.x < BKT_ROWS) lcur[threadIdx.x] = (r < N) ? off[r] : 0;
    __syncthreads();
    const int n = min(bkcur[b], BKT_CAP);
    const int2* bs = stage + (size_t)b * BKT_CAP;
    for (int i = threadIdx.x; i < n; i += blockDim.x) {
        const int2 ev = bs[i];
        const uint rl = ((uint)ev.x) >> 25;
        const int col = ev.x & 0x1ffffff;
        const int pos = atomicAdd(&lcur[rl], 1);
        adj[pos] = make_int2(col, ev.y);
    }
}

// fp32 embs -> bf16 x buffer (packed 2/uint), thread = 4 floats.
__global__ void cvt_kernel(const float4* __restrict__ src, uint2* __restrict__ dst, int n4) {
    const int i = blockIdx.x * blockDim.x + threadIdx.x;
    if (i >= n4) return;
    const float4 f = src[i];
    dst[i] = make_uint2(pk2(f.x, f.y), pk2(f.z, f.w));
}

// ---- SpMM: 16 lanes/row, 8 bf16 (uint4) per lane --------------------------

// msg = HG_up @ x  (bf16 in, bf16 out; fp32 accumulate)
__global__ void spmm_u_kernel(const int* __restrict__ off,
                              const int2* __restrict__ adj,
                              const uint4* __restrict__ xbf,
                              uint4* __restrict__ msgbf, int U) {
    const int g = threadIdx.x >> 4;
    const int lane = threadIdx.x & 15;
    const int row = blockIdx.x * 16 + g;
    if (row >= U) return;
    int k = off[row];
    const int end = off[row + 1];
    float acc[8] = {0, 0, 0, 0, 0, 0, 0, 0};
    for (; k + 1 < end; k += 2) {
        const int2 e0 = adj[k];
        const int2 e1 = adj[k + 1];
        const uint4 q0 = xbf[(size_t)e0.x * 16 + lane];
        const uint4 q1 = xbf[(size_t)e1.x * 16 + lane];
        fma8(acc, q0, __int_as_float(e0.y));
        fma8(acc, q1, __int_as_float(e1.y));
    }
    if (k < end) {
        const int2 e0 = adj[k];
        const uint4 q0 = xbf[(size_t)e0.x * 16 + lane];
        fma8(acc, q0, __int_as_float(e0.y));
    }
    uint4 o;
    o.x = pk2(acc[0], acc[1]);
    o.y = pk2(acc[2], acc[3]);
    o.z = pk2(acc[4], acc[5]);
    o.w = pk2(acc[6], acc[7]);
    msgbf[(size_t)row * 16 + lane] = o;
}

// prop = HG_pu @ msg ; x += prop (bf16 state) ; out = out_prev + w*prop (fp32)
__global__ void spmm_p_fused_kernel(const int* __restrict__ off,
                                    const int2* __restrict__ adj,
                                    const uint4* __restrict__ msgbf,
                                    uint4* __restrict__ xbf,
                                    const float4* __restrict__ embs,
                                    float4* __restrict__ out,
                                    float w, int first, int last, int U, int P) {
    const int g = threadIdx.x >> 4;
    const int lane = threadIdx.x & 15;
    const int row = blockIdx.x * 16 + g;
    if (row >= P) return;
    int k = off[U + row];
    const int end = off[U + row + 1];
    float acc[8] = {0, 0, 0, 0, 0, 0, 0, 0};
    for (; k + 1 < end; k += 2) {
        const int2 e0 = adj[k];
        const int2 e1 = adj[k + 1];
        const uint4 q0 = msgbf[(size_t)e0.x * 16 + lane];
        const uint4 q1 = msgbf[(size_t)e1.x * 16 + lane];
        fma8(acc, q0, __int_as_float(e0.y));
        fma8(acc, q1, __int_as_float(e1.y));
    }
    if (k < end) {
        const int2 e0 = adj[k];
        const uint4 q0 = msgbf[(size_t)e0.x * 16 + lane];
        fma8(acc, q0, __int_as_float(e0.y));
    }
    // residual update of bf16 x state (skip on last layer; no consumer)
    const size_t xi = (size_t)row * 16 + lane;
    if (!last) {
        const uint4 xq = xbf[xi];
        uint4 xn;
        xn.x = pk2(__uint_as_float(xq.x << 16) + acc[0],
                   __uint_as_float(xq.x & 0xffff0000u) + acc[1]);
        xn.y = pk2(__uint_as_float(xq.y << 16) + acc[2],
                   __uint_as_float(xq.y & 0xffff0000u) + acc[3]);
        xn.z = pk2(__uint_as_float(xq.z << 16) + acc[4],
                   __uint_as_float(xq.z & 0xffff0000u) + acc[5]);
        xn.w = pk2(__uint_as_float(xq.w << 16) + acc[6],
                   __uint_as_float(xq.w & 0xffff0000u) + acc[7]);
        xbf[xi] = xn;
    }
    // fp32 output accumulation: out = (first ? embs : out) + w * prop
    const size_t oi = (size_t)row * 32 + lane * 2;
    const float4* base = first ? embs : (const float4*)out;
    float4 a = base[oi];
    float4 b = base[oi + 1];
    a.x += w * acc[0]; a.y += w * acc[1]; a.z += w * acc[2]; a.w += w * acc[3];
    b.x += w * acc[4]; b.y += w * acc[5]; b.z += w * acc[6]; b.w += w * acc[7];
    out[oi] = a;
    out[oi + 1] = b;
}

// ---- launch ---------------------------------------------------------------

extern "C" void kernel_launch(void* const* d_in, const int* in_sizes, int n_in,
                              void* d_out, int out_size, void* d_ws, size_t ws_size,
                              hipStream_t stream) {
    const float* embs    = (const float*)d_in[0];
    const int*   up_rows = (const int*)d_in[2];
    const int*   up_cols = (const int*)d_in[3];
    const float* up_vals = (const float*)d_in[4];
    const float* pu_vals = (const float*)d_in[5];

    const int NNZ = in_sizes[2];
    const int P   = in_sizes[0] / DD;
    const int U   = 50000;            // fixed problem size (device scalar not host-readable)
    const int N   = U + P;
    const int NBK = (N + BKT_ROWS - 1) / BKT_ROWS;

    float* out = (float*)d_out;

    char* ws = (char*)d_ws;
    size_t o = 0;
    auto alloc = [&](size_t bytes) { size_t r = o; o = (o + bytes + 255) & ~255ULL; return r; };
    int*  bkcur = (int*) (ws + alloc((size_t)NBK * 4));
    int*  cnt   = (int*) (ws + alloc((size_t)N * 4));
    int*  off   = (int*) (ws + alloc((size_t)(N + 1) * 4));
    int*  bsums = (int*) (ws + alloc((size_t)SCAN_B * 4));
    int2* adj   = (int2*)(ws + alloc((size_t)2 * NNZ * 8));
    // stage (~57.7MB) is dead after pass2; xbf/msgbf alias it.
    const size_t stage_off = alloc((size_t)NBK * BKT_CAP * 8);
    int2*  stage = (int2*)(ws + stage_off);
    uint4* xbf   = (uint4*)(ws + stage_off);                         // P*128 bf16 = 25.6MB
    uint4* msgbf = (uint4*)(ws + stage_off + (size_t)P * DD * 2);    // U*128 bf16 = 12.8MB

    const int NB = (N + SCAN_B - 1) / SCAN_B;
    const int edge_blocks = (NNZ + 255) / 256;

    // --- CSR build ---
    hipMemsetAsync(bkcur, 0, (size_t)NBK * 4, stream);
    pass1_kernel<<<edge_blocks, 256, 0, stream>>>(up_rows, up_cols, up_vals, pu_vals,
                                                  bkcur, stage, NNZ, U);
    hist2_kernel<<<NBK, 256, 0, stream>>>(bkcur, stage, cnt, N);
    scan_blocks_kernel<<<NB, SCAN_B, 0, stream>>>(cnt, off, bsums, N);
    scan_sums_kernel<<<1, SCAN_B, 0, stream>>>(bsums, NB);
    scan_add_kernel<<<NB, SCAN_B, 0, stream>>>(off, bsums, cnt, N);
    pass2_kernel<<<NBK, 256, 0, stream>>>(bkcur, stage, off, adj, N);

    // --- bf16 x state init (after pass2: xbf aliases stage) ---
    const int n4 = P * DD / 4;
    cvt_kernel<<<(n4 + 255) / 256, 256, 0, stream>>>((const float4*)embs, (uint2*)xbf, n4);

    const int ublocks = (U + 15) / 16;
    const int pblocks = (P + 15) / 16;

    // --- 3 layers: out = embs + 0.75*p1 + 0.5*p2 + 0.25*p3 ---
    for (int layer = 0; layer < NUM_LAYERS; ++layer) {
        const float w = (float)(NUM_LAYERS - layer) / (NUM_LAYERS + 1);
        spmm_u_kernel<<<ublocks, 256, 0, stream>>>(off, adj, xbf, msgbf, U);
        spmm_p_fused_kernel<<<pblocks, 256, 0, stream>>>(
            off, adj, msgbf, xbf, (const float4*)embs, (float4*)out,
            w, layer == 0, layer == NUM_LAYERS - 1, U, P);
    }
}

// Round 5
// 605.554 us; speedup vs baseline: 2.2709x; 2.0893x over previous
//
#include <hip/hip_runtime.h>

// P = 100000 pois, U = 50000 users, NNZ = 2000000, D = 128, 3 layers.
// CSR build: block-aggregated binned scatter (LDS histogram + one global
// reservation atomic per (block, bucket, shard)), then bucket-local hist +
// scan + pass2. SpMM: bf16 gather operands, fp32 accumulate.
// out = x0 + 0.75*p1 + 0.5*p2 + 0.25*p3  ==  (x0+x1+x2+x3)/4.
#define DD 128
#define NUM_LAYERS 3
#define SCAN_B 1024
#define BKT_SHIFT 7
#define BKT_ROWS 128
#define LDS_BKT 1280     // >= nbkt = ceil(150000/128) = 1172
#define EPB 4096         // edges per pass1 block
#define SHARDS 4
#define CAP_SUB 1792     // per-shard bucket capacity (mean ~853, 16-sigma margin)

typedef unsigned int uint;

__device__ __forceinline__ uint f2bf(float f) {   // fp32 -> bf16 bits, RNE
    uint u = __float_as_uint(f);
    return (u + 0x7fffu + ((u >> 16) & 1u)) >> 16;
}
__device__ __forceinline__ uint pk2(float a, float b) {
    return f2bf(a) | (f2bf(b) << 16);
}
__device__ __forceinline__ void fma8(float acc[8], uint4 q, float v) {
    acc[0] += v * __uint_as_float(q.x << 16);
    acc[1] += v * __uint_as_float(q.x & 0xffff0000u);
    acc[2] += v * __uint_as_float(q.y << 16);
    acc[3] += v * __uint_as_float(q.y & 0xffff0000u);
    acc[4] += v * __uint_as_float(q.z << 16);
    acc[5] += v * __uint_as_float(q.z & 0xffff0000u);
    acc[6] += v * __uint_as_float(q.w << 16);
    acc[7] += v * __uint_as_float(q.w & 0xffff0000u);
}

// ---- pass1: block-aggregated scatter into sharded buckets -----------------

__global__ void pass1_kernel(const int* __restrict__ up_rows,
                             const int* __restrict__ up_cols,
                             const float* __restrict__ up_vals,
                             const float* __restrict__ pu_vals,
                             int* __restrict__ bkcur,
                             int2* __restrict__ stage,
                             int nnz, int U, int nbkt) {
    __shared__ int lcnt[LDS_BKT];
    const int tid = threadIdx.x;
    const int e0 = blockIdx.x * EPB;
    const int shard = blockIdx.x & (SHARDS - 1);
    for (int i = tid; i < nbkt; i += 256) lcnt[i] = 0;
    __syncthreads();
    // phase 1: LDS bucket histogram for this block's edge chunk
    #pragma unroll
    for (int i = 0; i < EPB / 256; ++i) {
        const int e = e0 + i * 256 + tid;
        if (e < nnz) {
            atomicAdd(&lcnt[up_rows[e] >> BKT_SHIFT], 1);
            atomicAdd(&lcnt[(U + up_cols[e]) >> BKT_SHIFT], 1);
        }
    }
    __syncthreads();
    // reserve: one global atomic per nonempty (bucket, shard); lcnt becomes base cursor
    for (int i = tid; i < nbkt; i += 256) {
        const int c = lcnt[i];
        lcnt[i] = c ? atomicAdd(&bkcur[i * SHARDS + shard], c) : 0;
    }
    __syncthreads();
    // phase 2: place entries via fast LDS cursors into the reserved windows
    #pragma unroll
    for (int i = 0; i < EPB / 256; ++i) {
        const int e = e0 + i * 256 + tid;
        if (e < nnz) {
            const int u = up_rows[e];
            const int p = up_cols[e];
            const int pc = U + p;
            int b = u >> BKT_SHIFT;
            int pos = atomicAdd(&lcnt[b], 1);
            if (pos < CAP_SUB)
                stage[((size_t)b * SHARDS + shard) * CAP_SUB + pos] =
                    make_int2(((u & (BKT_ROWS - 1)) << 25) | p, __float_as_int(up_vals[e]));
            b = pc >> BKT_SHIFT;
            pos = atomicAdd(&lcnt[b], 1);
            if (pos < CAP_SUB)
                stage[((size_t)b * SHARDS + shard) * CAP_SUB + pos] =
                    make_int2(((pc & (BKT_ROWS - 1)) << 25) | u, __float_as_int(pu_vals[e]));
        }
    }
}

// Bucket-local histogram -> per-row counts.
__global__ void hist2_kernel(const int* __restrict__ bkcur,
                             const int2* __restrict__ stage,
                             int* __restrict__ cnt, int N) {
    __shared__ int lc[BKT_ROWS];
    const int b = blockIdx.x;
    if (threadIdx.x < BKT_ROWS) lc[threadIdx.x] = 0;
    __syncthreads();
    for (int s = 0; s < SHARDS; ++s) {
        const int n = min(bkcur[b * SHARDS + s], CAP_SUB);
        const int2* bs = stage + ((size_t)b * SHARDS + s) * CAP_SUB;
        for (int i = threadIdx.x; i < n; i += blockDim.x)
            atomicAdd(&lc[((uint)bs[i].x) >> 25], 1);
    }
    __syncthreads();
    const int r = b * BKT_ROWS + threadIdx.x;
    if (threadIdx.x < BKT_ROWS && r < N) cnt[r] = lc[threadIdx.x];
}

__global__ void scan_blocks_kernel(const int* __restrict__ in, int* __restrict__ out,
                                   int* __restrict__ bsums, int n) {
    __shared__ int tmp[SCAN_B];
    const int tid = threadIdx.x;
    const int gid = blockIdx.x * SCAN_B + tid;
    const int v = (gid < n) ? in[gid] : 0;
    tmp[tid] = v;
    __syncthreads();
    for (int ofs = 1; ofs < SCAN_B; ofs <<= 1) {
        int t = (tid >= ofs) ? tmp[tid - ofs] : 0;
        __syncthreads();
        tmp[tid] += t;
        __syncthreads();
    }
    if (gid < n) out[gid] = tmp[tid] - v;
    if (tid == SCAN_B - 1) bsums[blockIdx.x] = tmp[tid];
}

__global__ void scan_sums_kernel(int* __restrict__ bsums, int nb) {
    __shared__ int tmp[SCAN_B];
    const int tid = threadIdx.x;
    const int v = (tid < nb) ? bsums[tid] : 0;
    tmp[tid] = v;
    __syncthreads();
    for (int ofs = 1; ofs < SCAN_B; ofs <<= 1) {
        int t = (tid >= ofs) ? tmp[tid - ofs] : 0;
        __syncthreads();
        tmp[tid] += t;
        __syncthreads();
    }
    if (tid < nb) bsums[tid] = tmp[tid] - v;
}

__global__ void scan_add_kernel(int* __restrict__ off, const int* __restrict__ bsums,
                                const int* __restrict__ cnt, int n) {
    const int gid = blockIdx.x * SCAN_B + threadIdx.x;
    if (gid >= n) return;
    const int v = off[gid] + bsums[blockIdx.x];
    off[gid] = v;
    if (gid == n - 1) off[n] = v + cnt[gid];
}

// pass2: sharded buckets -> final CSR (LDS row cursors, contiguous window).
__global__ void pass2_kernel(const int* __restrict__ bkcur,
                             const int2* __restrict__ stage,
                             const int* __restrict__ off,
                             int2* __restrict__ adj, int N) {
    __shared__ int lcur[BKT_ROWS];
    const int b = blockIdx.x;
    const int r = b * BKT_ROWS + threadIdx.x;
    if (threadIdx.x < BKT_ROWS) lcur[threadIdx.x] = (r < N) ? off[r] : 0;
    __syncthreads();
    for (int s = 0; s < SHARDS; ++s) {
        const int n = min(bkcur[b * SHARDS + s], CAP_SUB);
        const int2* bs = stage + ((size_t)b * SHARDS + s) * CAP_SUB;
        for (int i = threadIdx.x; i < n; i += blockDim.x) {
            const int2 ev = bs[i];
            const uint rl = ((uint)ev.x) >> 25;
            const int col = ev.x & 0x1ffffff;
            const int pos = atomicAdd(&lcur[rl], 1);
            adj[pos] = make_int2(col, ev.y);
        }
    }
}

// fp32 embs -> bf16 packed
__global__ void cvt_kernel(const float4* __restrict__ src, uint2* __restrict__ dst, int n4) {
    const int i = blockIdx.x * blockDim.x + threadIdx.x;
    if (i >= n4) return;
    const float4 f = src[i];
    dst[i] = make_uint2(pk2(f.x, f.y), pk2(f.z, f.w));
}

// ---- SpMM: 16 lanes/row, 8 bf16 (uint4) per lane --------------------------

__global__ void spmm_u_kernel(const int* __restrict__ off,
                              const int2* __restrict__ adj,
                              const uint4* __restrict__ xbf,
                              uint4* __restrict__ msgbf, int U) {
    const int g = threadIdx.x >> 4;
    const int lane = threadIdx.x & 15;
    const int row = blockIdx.x * 16 + g;
    if (row >= U) return;
    int k = off[row];
    const int end = off[row + 1];
    float acc[8] = {0, 0, 0, 0, 0, 0, 0, 0};
    for (; k + 1 < end; k += 2) {
        const int2 e0 = adj[k];
        const int2 e1 = adj[k + 1];
        const uint4 q0 = xbf[(size_t)e0.x * 16 + lane];
        const uint4 q1 = xbf[(size_t)e1.x * 16 + lane];
        fma8(acc, q0, __int_as_float(e0.y));
        fma8(acc, q1, __int_as_float(e1.y));
    }
    if (k < end) {
        const int2 e0 = adj[k];
        const uint4 q0 = xbf[(size_t)e0.x * 16 + lane];
        fma8(acc, q0, __int_as_float(e0.y));
    }
    uint4 o;
    o.x = pk2(acc[0], acc[1]);
    o.y = pk2(acc[2], acc[3]);
    o.z = pk2(acc[4], acc[5]);
    o.w = pk2(acc[6], acc[7]);
    msgbf[(size_t)row * 16 + lane] = o;
}

__global__ void spmm_p_fused_kernel(const int* __restrict__ off,
                                    const int2* __restrict__ adj,
                                    const uint4* __restrict__ msgbf,
                                    uint4* __restrict__ xbf,
                                    const float4* __restrict__ embs,
                                    float4* __restrict__ out,
                                    float w, int first, int last, int U, int P) {
    const int g = threadIdx.x >> 4;
    const int lane = threadIdx.x & 15;
    const int row = blockIdx.x * 16 + g;
    if (row >= P) return;
    int k = off[U + row];
    const int end = off[U + row + 1];
    float acc[8] = {0, 0, 0, 0, 0, 0, 0, 0};
    for (; k + 1 < end; k += 2) {
        const int2 e0 = adj[k];
        const int2 e1 = adj[k + 1];
        const uint4 q0 = msgbf[(size_t)e0.x * 16 + lane];
        const uint4 q1 = msgbf[(size_t)e1.x * 16 + lane];
        fma8(acc, q0, __int_as_float(e0.y));
        fma8(acc, q1, __int_as_float(e1.y));
    }
    if (k < end) {
        const int2 e0 = adj[k];
        const uint4 q0 = msgbf[(size_t)e0.x * 16 + lane];
        fma8(acc, q0, __int_as_float(e0.y));
    }
    const size_t xi = (size_t)row * 16 + lane;
    if (!last) {
        const uint4 xq = xbf[xi];
        uint4 xn;
        xn.x = pk2(__uint_as_float(xq.x << 16) + acc[0],
                   __uint_as_float(xq.x & 0xffff0000u) + acc[1]);
        xn.y = pk2(__uint_as_float(xq.y << 16) + acc[2],
                   __uint_as_float(xq.y & 0xffff0000u) + acc[3]);
        xn.z = pk2(__uint_as_float(xq.z << 16) + acc[4],
                   __uint_as_float(xq.z & 0xffff0000u) + acc[5]);
        xn.w = pk2(__uint_as_float(xq.w << 16) + acc[6],
                   __uint_as_float(xq.w & 0xffff0000u) + acc[7]);
        xbf[xi] = xn;
    }
    const size_t oi = (size_t)row * 32 + lane * 2;
    const float4* base = first ? embs : (const float4*)out;
    float4 a = base[oi];
    float4 b = base[oi + 1];
    a.x += w * acc[0]; a.y += w * acc[1]; a.z += w * acc[2]; a.w += w * acc[3];
    b.x += w * acc[4]; b.y += w * acc[5]; b.z += w * acc[6]; b.w += w * acc[7];
    out[oi] = a;
    out[oi + 1] = b;
}

// ---- launch ---------------------------------------------------------------

extern "C" void kernel_launch(void* const* d_in, const int* in_sizes, int n_in,
                              void* d_out, int out_size, void* d_ws, size_t ws_size,
                              hipStream_t stream) {
    const float* embs    = (const float*)d_in[0];
    const int*   up_rows = (const int*)d_in[2];
    const int*   up_cols = (const int*)d_in[3];
    const float* up_vals = (const float*)d_in[4];
    const float* pu_vals = (const float*)d_in[5];

    const int NNZ = in_sizes[2];
    const int P   = in_sizes[0] / DD;
    const int U   = 50000;            // fixed problem size (device scalar not host-readable)
    const int N   = U + P;
    const int NBKT = (N + BKT_ROWS - 1) / BKT_ROWS;   // 1172 <= LDS_BKT

    float* out = (float*)d_out;

    char* ws = (char*)d_ws;
    size_t o = 0;
    auto alloc = [&](size_t bytes) { size_t r = o; o = (o + bytes + 255) & ~255ULL; return r; };
    int*  bkcur = (int*) (ws + alloc((size_t)NBKT * SHARDS * 4));
    int*  cnt   = (int*) (ws + alloc((size_t)N * 4));
    int*  off   = (int*) (ws + alloc((size_t)(N + 1) * 4));
    int*  bsums = (int*) (ws + alloc((size_t)SCAN_B * 4));
    int2* adj   = (int2*)(ws + alloc((size_t)2 * NNZ * 8));
    // stage (~67 MB) is dead after pass2; xbf/msgbf alias it.
    const size_t stage_off = alloc((size_t)NBKT * SHARDS * CAP_SUB * 8);
    int2*  stage = (int2*)(ws + stage_off);
    uint4* xbf   = (uint4*)(ws + stage_off);                         // P*128 bf16
    uint4* msgbf = (uint4*)(ws + stage_off + (size_t)P * DD * 2);    // U*128 bf16

    const int NB = (N + SCAN_B - 1) / SCAN_B;

    // --- CSR build ---
    hipMemsetAsync(bkcur, 0, (size_t)NBKT * SHARDS * 4, stream);
    const int p1blocks = (NNZ + EPB - 1) / EPB;
    pass1_kernel<<<p1blocks, 256, 0, stream>>>(up_rows, up_cols, up_vals, pu_vals,
                                               bkcur, stage, NNZ, U, NBKT);
    hist2_kernel<<<NBKT, 256, 0, stream>>>(bkcur, stage, cnt, N);
    scan_blocks_kernel<<<NB, SCAN_B, 0, stream>>>(cnt, off, bsums, N);
    scan_sums_kernel<<<1, SCAN_B, 0, stream>>>(bsums, NB);
    scan_add_kernel<<<NB, SCAN_B, 0, stream>>>(off, bsums, cnt, N);
    pass2_kernel<<<NBKT, 256, 0, stream>>>(bkcur, stage, off, adj, N);

    // --- bf16 x state init (xbf aliases stage; runs after pass2) ---
    const int n4 = P * DD / 4;
    cvt_kernel<<<(n4 + 255) / 256, 256, 0, stream>>>((const float4*)embs, (uint2*)xbf, n4);

    const int ublocks = (U + 15) / 16;
    const int pblocks = (P + 15) / 16;

    // --- 3 layers: out = embs + 0.75*p1 + 0.5*p2 + 0.25*p3 ---
    for (int layer = 0; layer < NUM_LAYERS; ++layer) {
        const float w = (float)(NUM_LAYERS - layer) / (NUM_LAYERS + 1);
        spmm_u_kernel<<<ublocks, 256, 0, stream>>>(off, adj, xbf, msgbf, U);
        spmm_p_fused_kernel<<<pblocks, 256, 0, stream>>>(
            off, adj, msgbf, xbf, (const float4*)embs, (float4*)out,
            w, layer == 0, layer == NUM_LAYERS - 1, U, P);
    }
}

// Round 6
// 579.473 us; speedup vs baseline: 2.3731x; 1.0450x over previous
//
#include <hip/hip_runtime.h>

// P = 100000 pois, U = 50000 users, NNZ = 2000000, D = 128, 3 layers.
// CSR build: block-aggregated binned scatter (LDS histogram + one global
// reservation atomic per (block, bucket, shard)); bucket-total scan; pass2
// does per-row histogram + LDS scan + placement and emits off[] directly.
// SpMM: bf16 gather operands, fp32 accumulate, unroll-4 for MLP (memory-level
// parallelism). out = x0 + 0.75*p1 + 0.5*p2 + 0.25*p3 == (x0+x1+x2+x3)/4.
#define DD 128
#define NUM_LAYERS 3
#define SCAN_B 1024
#define BKT_SHIFT 7
#define BKT_ROWS 128
#define LDS_BKT 1280     // >= nbkt = ceil(150000/128) = 1172
#define EPB 4096         // edges per pass1 block
#define SHARDS 4
#define CAP_SUB 1792     // per-shard bucket capacity (u-mean 1280, ~14 sigma margin)

typedef unsigned int uint;

__device__ __forceinline__ uint f2bf(float f) {   // fp32 -> bf16 bits, RNE
    uint u = __float_as_uint(f);
    return (u + 0x7fffu + ((u >> 16) & 1u)) >> 16;
}
__device__ __forceinline__ uint pk2(float a, float b) {
    return f2bf(a) | (f2bf(b) << 16);
}
__device__ __forceinline__ void fma8(float acc[8], uint4 q, float v) {
    acc[0] += v * __uint_as_float(q.x << 16);
    acc[1] += v * __uint_as_float(q.x & 0xffff0000u);
    acc[2] += v * __uint_as_float(q.y << 16);
    acc[3] += v * __uint_as_float(q.y & 0xffff0000u);
    acc[4] += v * __uint_as_float(q.z << 16);
    acc[5] += v * __uint_as_float(q.z & 0xffff0000u);
    acc[6] += v * __uint_as_float(q.w << 16);
    acc[7] += v * __uint_as_float(q.w & 0xffff0000u);
}

// ---- pass1: block-aggregated scatter into sharded buckets -----------------

__global__ void pass1_kernel(const int* __restrict__ up_rows,
                             const int* __restrict__ up_cols,
                             const float* __restrict__ up_vals,
                             const float* __restrict__ pu_vals,
                             int* __restrict__ bkcur,
                             int2* __restrict__ stage,
                             int nnz, int U, int nbkt) {
    __shared__ int lcnt[LDS_BKT];
    const int tid = threadIdx.x;
    const int e0 = blockIdx.x * EPB;
    const int shard = blockIdx.x & (SHARDS - 1);
    for (int i = tid; i < nbkt; i += 256) lcnt[i] = 0;
    __syncthreads();
    #pragma unroll
    for (int i = 0; i < EPB / 256; ++i) {
        const int e = e0 + i * 256 + tid;
        if (e < nnz) {
            atomicAdd(&lcnt[up_rows[e] >> BKT_SHIFT], 1);
            atomicAdd(&lcnt[(U + up_cols[e]) >> BKT_SHIFT], 1);
        }
    }
    __syncthreads();
    for (int i = tid; i < nbkt; i += 256) {
        const int c = lcnt[i];
        lcnt[i] = c ? atomicAdd(&bkcur[i * SHARDS + shard], c) : 0;
    }
    __syncthreads();
    #pragma unroll
    for (int i = 0; i < EPB / 256; ++i) {
        const int e = e0 + i * 256 + tid;
        if (e < nnz) {
            const int u = up_rows[e];
            const int p = up_cols[e];
            const int pc = U + p;
            int b = u >> BKT_SHIFT;
            int pos = atomicAdd(&lcnt[b], 1);
            if (pos < CAP_SUB)
                stage[((size_t)b * SHARDS + shard) * CAP_SUB + pos] =
                    make_int2(((u & (BKT_ROWS - 1)) << 25) | p, __float_as_int(up_vals[e]));
            b = pc >> BKT_SHIFT;
            pos = atomicAdd(&lcnt[b], 1);
            if (pos < CAP_SUB)
                stage[((size_t)b * SHARDS + shard) * CAP_SUB + pos] =
                    make_int2(((pc & (BKT_ROWS - 1)) << 25) | u, __float_as_int(pu_vals[e]));
        }
    }
}

// ---- bucket-total scan (1172 elements) ------------------------------------

__global__ void tot_kernel(const int* __restrict__ bkcur, int* __restrict__ tot, int nbkt) {
    const int b = blockIdx.x * blockDim.x + threadIdx.x;
    if (b >= nbkt) return;
    int t = 0;
    #pragma unroll
    for (int s = 0; s < SHARDS; ++s) t += min(bkcur[b * SHARDS + s], CAP_SUB);
    tot[b] = t;
}

__global__ void scan_blocks_kernel(const int* __restrict__ in, int* __restrict__ out,
                                   int* __restrict__ bsums, int n) {
    __shared__ int tmp[SCAN_B];
    const int tid = threadIdx.x;
    const int gid = blockIdx.x * SCAN_B + tid;
    const int v = (gid < n) ? in[gid] : 0;
    tmp[tid] = v;
    __syncthreads();
    for (int ofs = 1; ofs < SCAN_B; ofs <<= 1) {
        int t = (tid >= ofs) ? tmp[tid - ofs] : 0;
        __syncthreads();
        tmp[tid] += t;
        __syncthreads();
    }
    if (gid < n) out[gid] = tmp[tid] - v;
    if (tid == SCAN_B - 1) bsums[blockIdx.x] = tmp[tid];
}

__global__ void scan_sums_kernel(int* __restrict__ bsums, int nb) {
    __shared__ int tmp[SCAN_B];
    const int tid = threadIdx.x;
    const int v = (tid < nb) ? bsums[tid] : 0;
    tmp[tid] = v;
    __syncthreads();
    for (int ofs = 1; ofs < SCAN_B; ofs <<= 1) {
        int t = (tid >= ofs) ? tmp[tid - ofs] : 0;
        __syncthreads();
        tmp[tid] += t;
        __syncthreads();
    }
    if (tid < nb) bsums[tid] = tmp[tid] - v;
}

__global__ void scan_add_kernel(int* __restrict__ off, const int* __restrict__ bsums,
                                const int* __restrict__ cnt, int n) {
    const int gid = blockIdx.x * SCAN_B + threadIdx.x;
    if (gid >= n) return;
    const int v = off[gid] + bsums[blockIdx.x];
    off[gid] = v;
    if (gid == n - 1) off[n] = v + cnt[gid];
}

// ---- pass2: per-row hist + LDS scan + placement; emits off[] --------------

__global__ void pass2_kernel(const int* __restrict__ bkcur,
                             const int2* __restrict__ stage,
                             const int* __restrict__ bkbase,
                             int* __restrict__ off,
                             int2* __restrict__ adj, int N, int nbkt) {
    __shared__ int ca[BKT_ROWS], cb[BKT_ROWS], lcur[BKT_ROWS];
    const int b = blockIdx.x;
    const int tid = threadIdx.x;
    if (tid < BKT_ROWS) ca[tid] = 0;
    __syncthreads();
    int ns[SHARDS];
    const int2* bs[SHARDS];
    #pragma unroll
    for (int s = 0; s < SHARDS; ++s) {
        ns[s] = min(bkcur[b * SHARDS + s], CAP_SUB);
        bs[s] = stage + ((size_t)b * SHARDS + s) * CAP_SUB;
    }
    #pragma unroll
    for (int s = 0; s < SHARDS; ++s)
        for (int i = tid; i < ns[s]; i += 256)
            atomicAdd(&ca[((uint)bs[s][i].x) >> 25], 1);
    __syncthreads();
    // inclusive scan of ca (7 ping-pong steps); result lands in src.
    int* src = ca; int* dst = cb;
    for (int ofs = 1; ofs < BKT_ROWS; ofs <<= 1) {
        if (tid < BKT_ROWS)
            dst[tid] = src[tid] + (tid >= ofs ? src[tid - ofs] : 0);
        __syncthreads();
        int* t = src; src = dst; dst = t;
    }
    const int base = bkbase[b];
    if (tid < BKT_ROWS) {
        const int excl = base + (tid ? src[tid - 1] : 0);
        lcur[tid] = excl;
        const int r = b * BKT_ROWS + tid;
        if (r < N) off[r] = excl;
    }
    if (b == 0 && tid == 0) off[N] = bkbase[nbkt];
    __syncthreads();
    #pragma unroll
    for (int s = 0; s < SHARDS; ++s)
        for (int i = tid; i < ns[s]; i += 256) {
            const int2 ev = bs[s][i];
            const int pos = atomicAdd(&lcur[((uint)ev.x) >> 25], 1);
            adj[pos] = make_int2(ev.x & 0x1ffffff, ev.y);
        }
}

// fp32 embs -> bf16 packed
__global__ void cvt_kernel(const float4* __restrict__ src, uint2* __restrict__ dst, int n4) {
    const int i = blockIdx.x * blockDim.x + threadIdx.x;
    if (i >= n4) return;
    const float4 f = src[i];
    dst[i] = make_uint2(pk2(f.x, f.y), pk2(f.z, f.w));
}

// ---- SpMM: 16 lanes/row, 8 bf16 (uint4) per lane, unroll-4 ----------------

__global__ void spmm_u_kernel(const int* __restrict__ off,
                              const int2* __restrict__ adj,
                              const uint4* __restrict__ xbf,
                              uint4* __restrict__ msgbf, int U) {
    const int g = threadIdx.x >> 4;
    const int lane = threadIdx.x & 15;
    const int row = blockIdx.x * 16 + g;
    if (row >= U) return;
    int k = off[row];
    const int end = off[row + 1];
    float acc[8] = {0, 0, 0, 0, 0, 0, 0, 0};
    for (; k + 3 < end; k += 4) {
        const int2 e0 = adj[k];
        const int2 e1 = adj[k + 1];
        const int2 e2 = adj[k + 2];
        const int2 e3 = adj[k + 3];
        const uint4 q0 = xbf[(size_t)e0.x * 16 + lane];
        const uint4 q1 = xbf[(size_t)e1.x * 16 + lane];
        const uint4 q2 = xbf[(size_t)e2.x * 16 + lane];
        const uint4 q3 = xbf[(size_t)e3.x * 16 + lane];
        fma8(acc, q0, __int_as_float(e0.y));
        fma8(acc, q1, __int_as_float(e1.y));
        fma8(acc, q2, __int_as_float(e2.y));
        fma8(acc, q3, __int_as_float(e3.y));
    }
    for (; k < end; ++k) {
        const int2 e = adj[k];
        const uint4 q = xbf[(size_t)e.x * 16 + lane];
        fma8(acc, q, __int_as_float(e.y));
    }
    uint4 o;
    o.x = pk2(acc[0], acc[1]);
    o.y = pk2(acc[2], acc[3]);
    o.z = pk2(acc[4], acc[5]);
    o.w = pk2(acc[6], acc[7]);
    msgbf[(size_t)row * 16 + lane] = o;
}

__global__ void spmm_p_fused_kernel(const int* __restrict__ off,
                                    const int2* __restrict__ adj,
                                    const uint4* __restrict__ msgbf,
                                    uint4* __restrict__ xbf,
                                    const float4* __restrict__ embs,
                                    float4* __restrict__ out,
                                    float w, int first, int last, int U, int P) {
    const int g = threadIdx.x >> 4;
    const int lane = threadIdx.x & 15;
    const int row = blockIdx.x * 16 + g;
    if (row >= P) return;
    int k = off[U + row];
    const int end = off[U + row + 1];
    float acc[8] = {0, 0, 0, 0, 0, 0, 0, 0};
    for (; k + 3 < end; k += 4) {
        const int2 e0 = adj[k];
        const int2 e1 = adj[k + 1];
        const int2 e2 = adj[k + 2];
        const int2 e3 = adj[k + 3];
        const uint4 q0 = msgbf[(size_t)e0.x * 16 + lane];
        const uint4 q1 = msgbf[(size_t)e1.x * 16 + lane];
        const uint4 q2 = msgbf[(size_t)e2.x * 16 + lane];
        const uint4 q3 = msgbf[(size_t)e3.x * 16 + lane];
        fma8(acc, q0, __int_as_float(e0.y));
        fma8(acc, q1, __int_as_float(e1.y));
        fma8(acc, q2, __int_as_float(e2.y));
        fma8(acc, q3, __int_as_float(e3.y));
    }
    for (; k < end; ++k) {
        const int2 e = adj[k];
        const uint4 q = msgbf[(size_t)e.x * 16 + lane];
        fma8(acc, q, __int_as_float(e.y));
    }
    const size_t xi = (size_t)row * 16 + lane;
    if (!last) {
        const uint4 xq = xbf[xi];
        uint4 xn;
        xn.x = pk2(__uint_as_float(xq.x << 16) + acc[0],
                   __uint_as_float(xq.x & 0xffff0000u) + acc[1]);
        xn.y = pk2(__uint_as_float(xq.y << 16) + acc[2],
                   __uint_as_float(xq.y & 0xffff0000u) + acc[3]);
        xn.z = pk2(__uint_as_float(xq.z << 16) + acc[4],
                   __uint_as_float(xq.z & 0xffff0000u) + acc[5]);
        xn.w = pk2(__uint_as_float(xq.w << 16) + acc[6],
                   __uint_as_float(xq.w & 0xffff0000u) + acc[7]);
        xbf[xi] = xn;
    }
    const size_t oi = (size_t)row * 32 + lane * 2;
    const float4* base = first ? embs : (const float4*)out;
    float4 a = base[oi];
    float4 b = base[oi + 1];
    a.x += w * acc[0]; a.y += w * acc[1]; a.z += w * acc[2]; a.w += w * acc[3];
    b.x += w * acc[4]; b.y += w * acc[5]; b.z += w * acc[6]; b.w += w * acc[7];
    out[oi] = a;
    out[oi + 1] = b;
}

// ---- launch ---------------------------------------------------------------

extern "C" void kernel_launch(void* const* d_in, const int* in_sizes, int n_in,
                              void* d_out, int out_size, void* d_ws, size_t ws_size,
                              hipStream_t stream) {
    const float* embs    = (const float*)d_in[0];
    const int*   up_rows = (const int*)d_in[2];
    const int*   up_cols = (const int*)d_in[3];
    const float* up_vals = (const float*)d_in[4];
    const float* pu_vals = (const float*)d_in[5];

    const int NNZ = in_sizes[2];
    const int P   = in_sizes[0] / DD;
    const int U   = 50000;            // fixed problem size (device scalar not host-readable)
    const int N   = U + P;
    const int NBKT = (N + BKT_ROWS - 1) / BKT_ROWS;   // 1172 <= LDS_BKT

    float* out = (float*)d_out;

    char* ws = (char*)d_ws;
    size_t o = 0;
    auto alloc = [&](size_t bytes) { size_t r = o; o = (o + bytes + 255) & ~255ULL; return r; };
    int*  bkcur  = (int*) (ws + alloc((size_t)NBKT * SHARDS * 4));
    int*  tot    = (int*) (ws + alloc((size_t)NBKT * 4));
    int*  bkbase = (int*) (ws + alloc((size_t)(NBKT + 1) * 4));
    int*  bsums  = (int*) (ws + alloc((size_t)SCAN_B * 4));
    int*  off    = (int*) (ws + alloc((size_t)(N + 1) * 4));
    int2* adj    = (int2*)(ws + alloc((size_t)2 * NNZ * 8));
    // stage (~67 MB) is dead after pass2; xbf/msgbf alias it.
    const size_t stage_off = alloc((size_t)NBKT * SHARDS * CAP_SUB * 8);
    int2*  stage = (int2*)(ws + stage_off);
    uint4* xbf   = (uint4*)(ws + stage_off);                         // P*128 bf16
    uint4* msgbf = (uint4*)(ws + stage_off + (size_t)P * DD * 2);    // U*128 bf16

    // --- CSR build ---
    hipMemsetAsync(bkcur, 0, (size_t)NBKT * SHARDS * 4, stream);
    const int p1blocks = (NNZ + EPB - 1) / EPB;
    pass1_kernel<<<p1blocks, 256, 0, stream>>>(up_rows, up_cols, up_vals, pu_vals,
                                               bkcur, stage, NNZ, U, NBKT);
    tot_kernel<<<(NBKT + 255) / 256, 256, 0, stream>>>(bkcur, tot, NBKT);
    const int NBb = (NBKT + SCAN_B - 1) / SCAN_B;    // = 2
    scan_blocks_kernel<<<NBb, SCAN_B, 0, stream>>>(tot, bkbase, bsums, NBKT);
    scan_sums_kernel<<<1, SCAN_B, 0, stream>>>(bsums, NBb);
    scan_add_kernel<<<NBb, SCAN_B, 0, stream>>>(bkbase, bsums, tot, NBKT);
    pass2_kernel<<<NBKT, 256, 0, stream>>>(bkcur, stage, bkbase, off, adj, N, NBKT);

    // --- bf16 x state init (xbf aliases stage; runs after pass2) ---
    const int n4 = P * DD / 4;
    cvt_kernel<<<(n4 + 255) / 256, 256, 0, stream>>>((const float4*)embs, (uint2*)xbf, n4);

    const int ublocks = (U + 15) / 16;
    const int pblocks = (P + 15) / 16;

    // --- 3 layers: out = embs + 0.75*p1 + 0.5*p2 + 0.25*p3 ---
    for (int layer = 0; layer < NUM_LAYERS; ++layer) {
        const float w = (float)(NUM_LAYERS - layer) / (NUM_LAYERS + 1);
        spmm_u_kernel<<<ublocks, 256, 0, stream>>>(off, adj, xbf, msgbf, U);
        spmm_p_fused_kernel<<<pblocks, 256, 0, stream>>>(
            off, adj, msgbf, xbf, (const float4*)embs, (float4*)out,
            w, layer == 0, layer == NUM_LAYERS - 1, U, P);
    }
}